// Round 5
// baseline (735.842 us; speedup 1.0000x reference)
//
#include <hip/hip_runtime.h>

typedef __bf16 bf16;
typedef __bf16 bf16x4 __attribute__((ext_vector_type(4)));
typedef __bf16 bf16x8 __attribute__((ext_vector_type(8)));
typedef float  floatx4 __attribute__((ext_vector_type(4)));

#define L_SEQ   2048
#define C_SEQ   256
#define S_SEQ   2304
#define NBATCH  4
#define NHEAD   16
#define DHEAD   64
#define DMODEL  1024
#define RMS_EPS 1.1920928955078125e-07f
#define LIN_EPS 1e-6f

// async global->LDS, 16B per lane; LDS dest must be wave-uniform (+lane*16)
__device__ __forceinline__ void gload_lds16(const void* g, void* l) {
  __builtin_amdgcn_global_load_lds(
      (const __attribute__((address_space(1))) void*)g,
      (__attribute__((address_space(3))) void*)l, 16, 0, 0);
}

// ---------------------------------------------------------------- prep jobs
__device__ __forceinline__ void transpose_job(
    const float* __restrict__ src, bf16* __restrict__ dst,
    int R, int C, int tb, bf16 (*tile)[33]) {
  int tilesx = C >> 5;
  int c0 = (tb % tilesx) * 32, r0 = (tb / tilesx) * 32;
  int tx = threadIdx.x & 31, ty = threadIdx.x >> 5;
  for (int i = ty; i < 32; i += 8)
    tile[i][tx] = (bf16)src[(size_t)(r0 + i) * C + c0 + tx];
  __syncthreads();
  for (int i = ty; i < 32; i += 8)
    dst[(size_t)(c0 + i) * R + r0 + tx] = tile[tx][i];
}

__device__ __forceinline__ void convert_job(
    const float* __restrict__ src, bf16* __restrict__ dst, int tb) {
  size_t i = ((size_t)tb * 256 + threadIdx.x) * 8;
  floatx4 a = *(const floatx4*)(src + i);
  floatx4 b = *(const floatx4*)(src + i + 4);
  bf16x8 o;
#pragma unroll
  for (int j = 0; j < 4; j++) { o[j] = (bf16)a[j]; o[4 + j] = (bf16)b[j]; }
  *(bf16x8*)(dst + i) = o;
}

// One fused kernel for all independent prep work (block ranges in comments)
__global__ __launch_bounds__(256) void prep(
    const float* __restrict__ Wqkv, const float* __restrict__ cWqkv,
    const float* __restrict__ Wout, const float* __restrict__ cWout,
    const float* __restrict__ x, const float* __restrict__ ctx,
    const int* __restrict__ mask, const int* __restrict__ spos,
    bf16* __restrict__ WqkvT, bf16* __restrict__ cWqkvT,
    bf16* __restrict__ WoutT, bf16* __restrict__ cWoutT,
    bf16* __restrict__ xbf, bf16* __restrict__ cbf,
    float* __restrict__ vkw, float* __restrict__ rope,
    int* __restrict__ anym) {
  __shared__ bf16 tile[32][33];
  __shared__ int sh;
  int b = blockIdx.x;
  if (b < 3072) { transpose_job(Wqkv, WqkvT, 1024, 3072, b, tile); return; }
  b -= 3072;
  if (b < 3072) { transpose_job(cWqkv, cWqkvT, 1024, 3072, b, tile); return; }
  b -= 3072;
  if (b < 1024) { transpose_job(Wout, WoutT, 1024, 1024, b, tile); return; }
  b -= 1024;
  if (b < 1024) { transpose_job(cWout, cWoutT, 1024, 1024, b, tile); return; }
  b -= 1024;
  if (b < 4096) { convert_job(x, xbf, b); return; }
  b -= 4096;
  if (b < 512) { convert_job(ctx, cbf, b); return; }
  b -= 512;
  if (b < 260) {
    int i = b * 1024 + threadIdx.x * 4;
    *(floatx4*)(vkw + i) = floatx4{0.f, 0.f, 0.f, 0.f};
    return;
  }
  b -= 260;
  if (b < 2048) {
    // rope table: token = b*4 + t/64 (x tokens only), j = t&63, fi = j>>1
    int t = threadIdx.x;
    int tok = b * 4 + (t >> 6);
    int bb = tok >> 11, s = tok & 2047;
    int j = t & 63, fi = j >> 1;
    float ang = (float)(spos[bb] + s) * expf((float)fi * -0.28782313662425572f);
    rope[(size_t)tok * 64 + j] = (j & 1) ? sinf(ang) : cosf(ang);
    return;
  }
  b -= 2048;
  // anymask: any(mask[b][0][:])
  int a = 0;
  size_t base = (size_t)b * L_SEQ * L_SEQ;
  for (int j = threadIdx.x; j < L_SEQ; j += 256) a |= mask[base + j];
  if (threadIdx.x == 0) sh = 0;
  __syncthreads();
  if (a) atomicOr(&sh, 1);
  __syncthreads();
  if (threadIdx.x == 0) anym[b] = sh;
}

// ---------------------------------------------------------------- GEMM
// T256: 256x256 tile BK=32, 512 thr (8 waves 2Mx4N), dbuf LDS 64 KiB ->
//   2 blocks/CU so drains overlap across blocks.
// !T256: 128x128 tile BK=32, 256 thr (4 waves 2x2), dbuf 32 KiB -> 4/CU
//   (for the N=1024 out-projection where a 256^2 grid would underfill).
// 2-phase: stage next tile into other buf, read+MFMA current, one barrier.
// Swizzle (64B rows): logical colbyte c at row r stored at c^((r&3)<<4);
// applied via pre-swizzled global source + swizzled ds_read (involution).
// Pair launch: by < ybound -> part 1, else part 2. SCATTER as before.
template <bool SCATTER, bool T256>
__global__ __launch_bounds__(T256 ? 512 : 256, 4) void gemm_bias(
    const bf16* __restrict__ A1, const bf16* __restrict__ A2,
    const bf16* __restrict__ B1t, const bf16* __restrict__ B2t,
    const float* __restrict__ bias1, const float* __restrict__ bias2,
    bf16* __restrict__ C1, bf16* __restrict__ C2,
    bf16* __restrict__ qs, bf16* __restrict__ ks, bf16* __restrict__ vs,
    int N, int K, int ybound,
    int rpb1, int soff1, int rpb2, int soff2) {
  constexpr int BMv = T256 ? 256 : 128;
  constexpr int MT  = T256 ? 8 : 4;
  constexpr int WRS = T256 ? 128 : 64;
  __shared__ bf16 As[2][BMv * 32];
  __shared__ bf16 Bs[2][BMv * 32];

  // XCD-aware swizzle (all grids have nwg % 8 == 0)
  int nwg = gridDim.x * gridDim.y;
  int wg = blockIdx.y * gridDim.x + blockIdx.x;
  int cpx = nwg >> 3;
  wg = (wg & 7) * cpx + (wg >> 3);
  int bx = wg % gridDim.x, by = wg / gridDim.x;
  int n0 = bx * BMv;
  const bf16 *Ap, *Bt;
  const float* bias;
  bf16* Cp;
  int m0, rpb, soff;
  if (by < ybound) {
    Ap = A1; Bt = B1t; bias = bias1; Cp = C1;
    m0 = by * BMv; rpb = rpb1; soff = soff1;
  } else {
    Ap = A2; Bt = B2t; bias = bias2; Cp = C2;
    m0 = (by - ybound) * BMv; rpb = rpb2; soff = soff2;
  }

  int t = threadIdx.x, lane = t & 63, w = t >> 6;
  int wr, wc;
  if constexpr (T256) { wr = w >> 2; wc = w & 3; }
  else                { wr = w >> 1; wc = w & 1; }
  int l16 = lane & 15, l4 = lane >> 4;

  // staging: chunk c = w*2+j covers rows [c*16, c*16+16) (64B rows); lane l
  // -> row c*16 + (l>>2). Global col pre-swizzled: el = ((l&3)^((l>>2)&3))*8.
  int crow = w * 32 + (lane >> 2);
  int scol = (((lane & 3) ^ ((lane >> 2) & 3)) << 3);
  const bf16* Ab = Ap + (size_t)(m0 + crow) * K + scol;
  const bf16* Bb = Bt + (size_t)(n0 + crow) * K + scol;

  auto stage = [&](int buf, int kb) {
#pragma unroll
    for (int j = 0; j < 2; j++) {
      gload_lds16(Ab + (size_t)(j * 16) * K + kb, (char*)As[buf] + (w * 2 + j) * 1024);
      gload_lds16(Bb + (size_t)(j * 16) * K + kb, (char*)Bs[buf] + (w * 2 + j) * 1024);
    }
  };

  // ds_read: logical col el = l4*8, row = base + l16 -> swizzled el offset
  int co = (l4 * 8) ^ ((l16 & 3) << 3);
  int rba = (wr * WRS + l16) * 32 + co;   // + mt*512
  int rbb = (wc * 64 + l16) * 32 + co;    // + nt*512

  floatx4 acc[MT][4] = {};
  stage(0, 0);
  __syncthreads();
  int NTt = K >> 5;
  for (int tt = 0; tt < NTt; ++tt) {
    int p = tt & 1;
    if (tt + 1 < NTt) stage(p ^ 1, (tt + 1) << 5);  // issue-early prefetch
    bf16x8 bfr[4];
#pragma unroll
    for (int nt = 0; nt < 4; nt++) bfr[nt] = *(const bf16x8*)&Bs[p][rbb + nt * 512];
    __builtin_amdgcn_s_setprio(1);
#pragma unroll
    for (int mt = 0; mt < MT; mt++) {
      bf16x8 a = *(const bf16x8*)&As[p][rba + mt * 512];
#pragma unroll
      for (int nt = 0; nt < 4; nt++)
        acc[mt][nt] = __builtin_amdgcn_mfma_f32_16x16x32_bf16(a, bfr[nt], acc[mt][nt], 0, 0, 0);
    }
    __builtin_amdgcn_s_setprio(0);
    __syncthreads();   // drains stage vmcnt; sibling block(s) overlap this
  }

  // epilogue: D[row=(l>>4)*4+r][col=l&15] per 16x16 tile
#pragma unroll
  for (int mt = 0; mt < MT; mt++)
#pragma unroll
    for (int nt = 0; nt < 4; nt++) {
      int col = n0 + wc * 64 + nt * 16 + l16;
      float bval = bias[col];
      if constexpr (SCATTER) {
        int which = col >> 10;
        int h = (col >> 6) & 15;
        int dh = col & 63;
        int rmask = (1 << rpb) - 1;
        if (which == 2) {
          int rw0 = m0 + wr * WRS + mt * 16 + l4 * 4;
          int b = rw0 >> rpb;
          int s = soff + (rw0 & rmask);
          bf16x4 o;
#pragma unroll
          for (int r = 0; r < 4; r++) o[r] = (bf16)(acc[mt][nt][r] + bval);
          *(bf16x4*)(vs + ((size_t)(b * NHEAD + h) * DHEAD + dh) * S_SEQ + s) = o;
        } else {
          bf16* dst = which == 0 ? qs : ks;
#pragma unroll
          for (int r = 0; r < 4; r++) {
            int rw = m0 + wr * WRS + mt * 16 + l4 * 4 + r;
            int b = rw >> rpb;
            int s = soff + (rw & rmask);
            dst[((size_t)(b * NHEAD + h) * S_SEQ + s) * DHEAD + dh] =
                (bf16)(acc[mt][nt][r] + bval);
          }
        }
      } else {
#pragma unroll
        for (int r = 0; r < 4; r++) {
          int rw = m0 + wr * WRS + mt * 16 + l4 * 4 + r;
          Cp[(size_t)rw * N + col] = (bf16)(acc[mt][nt][r] + bval);
        }
      }
    }
}

// ---------------------------------------------------------------- qkv post
__global__ __launch_bounds__(256) void qkv_post(
    bf16* __restrict__ qs, bf16* __restrict__ ks,
    const int* __restrict__ mask, const float* __restrict__ rope,
    const int* __restrict__ anym,
    const float* __restrict__ g_q, const float* __restrict__ g_k,
    const float* __restrict__ cg_q, const float* __restrict__ cg_k) {
  int g = blockIdx.x, t = threadIdx.x;
  bool is_ctx = g >= NBATCH * L_SEQ;
  int b, s;
  const float *gq, *gk;
  float mval;
  if (!is_ctx) {
    b = g >> 11;
    int l = g & 2047;
    s = l;
    mval = mask[(size_t)b * L_SEQ * L_SEQ + l] ? 1.f : 0.f;  // mask[b][0][l]
    gq = g_q; gk = g_k;
  } else {
    int gg = g - NBATCH * L_SEQ;
    b = gg >> 8;
    s = L_SEQ + (gg & 255);
    mval = anym[b] ? 1.f : 0.f;
    gq = cg_q; gk = cg_k;
  }
  int d0 = t * 4;
  int h = t >> 4, dh = (t & 15) * 4;            // h*64+dh == d0
  size_t base = ((size_t)(b * NHEAD + h) * S_SEQ + s) * DHEAD + dh;
  bf16x4 q4 = *(const bf16x4*)(qs + base);
  bf16x4 k4 = *(const bf16x4*)(ks + base);
  float qv[4], kv[4], pq = 0.f, pk = 0.f;
#pragma unroll
  for (int i = 0; i < 4; i++) {
    qv[i] = (float)q4[i]; kv[i] = (float)k4[i];
    pq += qv[i] * qv[i];  pk += kv[i] * kv[i];
  }
  int lane = t & 63, w = t >> 6;
  for (int off = 32; off > 0; off >>= 1) {
    pq += __shfl_down(pq, off, 64);
    pk += __shfl_down(pk, off, 64);
  }
  __shared__ float red[8];
  if (lane == 0) { red[w] = pq; red[4 + w] = pk; }
  __syncthreads();
  float sq = red[0] + red[1] + red[2] + red[3];
  float sk = red[4] + red[5] + red[6] + red[7];
  float scq = rsqrtf(sq * (1.f / DMODEL) + RMS_EPS);
  float sck = rsqrtf(sk * (1.f / DMODEL) + RMS_EPS);
#pragma unroll
  for (int i = 0; i < 4; i++) {
    qv[i] *= scq * gq[d0 + i];
    kv[i] *= sck * gk[d0 + i];
  }
  if (!is_ctx) {
    floatx4 tb4 = *(const floatx4*)&rope[((size_t)(b << 11 | s)) * 64 + dh];
#pragma unroll
    for (int pr = 0; pr < 2; pr++) {
      float cc = tb4[2 * pr], ss = tb4[2 * pr + 1];
      float t0 = qv[2 * pr], t1 = qv[2 * pr + 1];
      qv[2 * pr]     = t0 * cc - t1 * ss;
      qv[2 * pr + 1] = t0 * ss + t1 * cc;
      t0 = kv[2 * pr]; t1 = kv[2 * pr + 1];
      kv[2 * pr]     = t0 * cc - t1 * ss;
      kv[2 * pr + 1] = t0 * ss + t1 * cc;
    }
  }
  bf16x4 qo, ko;
#pragma unroll
  for (int i = 0; i < 4; i++) {
    qo[i] = (bf16)fmaxf(qv[i], 0.f);
    ko[i] = (bf16)(fmaxf(kv[i], 0.f) * mval);
  }
  *(bf16x4*)(qs + base) = qo;
  *(bf16x4*)(ks + base) = ko;
}

// ---------------------------------------------------------------- vk (MFMA)
// vk[bh][e][d] = sum_s vT[bh][e][s] * kf[bh][s][d]; row e=64: sum_s kf[s][d].
// 1-barrier reg-staged double-buffer. Partials atomicAdd into zeroed vkw.
#define VK_CH   12
#define VK_SPAN (S_SEQ / VK_CH)   // 192 = 6 K-steps of 32
__global__ __launch_bounds__(256) void vk_mfma(
    const bf16* __restrict__ vT, const bf16* __restrict__ kf,
    float* __restrict__ vk) {
  __shared__ bf16 Vs[2][64][40];
  __shared__ bf16 Ks[2][64][40];   // Ks[d][s]
  int bh = blockIdx.x / VK_CH, chunk = blockIdx.x % VK_CH;
  int t = threadIdx.x, lane = t & 63, w = t >> 6;
  int l16 = lane & 15, l4 = lane >> 4;
  const bf16* vp = vT + (size_t)bh * DHEAD * S_SEQ;
  const bf16* kp = kf + (size_t)bh * S_SEQ * DHEAD;
  int s_begin = chunk * VK_SPAN;
  int ve = t >> 2, vso = (t & 3) * 8;        // v staging: row e, col offset
  int ks_s = t & 31, kd0 = (t >> 5) * 8;     // kf staging: s-slice, d-octet
  floatx4 acc[4] = {};
  float dsum[8] = {};
  bf16x8 vv = *(const bf16x8*)(vp + (size_t)ve * S_SEQ + s_begin + vso);
  bf16x8 kv = *(const bf16x8*)(kp + (size_t)(s_begin + ks_s) * DHEAD + kd0);
  for (int st = 0; st < VK_SPAN; st += 32) {
    int cur = (st >> 5) & 1;
    *(bf16x8*)&Vs[cur][ve][vso] = vv;
#pragma unroll
    for (int j = 0; j < 8; j++) {
      Ks[cur][kd0 + j][ks_s] = kv[j];
      dsum[j] += (float)kv[j];
    }
    if (st + 32 < VK_SPAN) {
      int s0 = s_begin + st + 32;
      vv = *(const bf16x8*)(vp + (size_t)ve * S_SEQ + s0 + vso);
      kv = *(const bf16x8*)(kp + (size_t)(s0 + ks_s) * DHEAD + kd0);
    }
    __syncthreads();
    bf16x8 af = *(const bf16x8*)&Vs[cur][w * 16 + l16][l4 * 8];
#pragma unroll
    for (int nt = 0; nt < 4; nt++) {
      bf16x8 bfr = *(const bf16x8*)&Ks[cur][nt * 16 + l16][l4 * 8];
      acc[nt] = __builtin_amdgcn_mfma_f32_16x16x32_bf16(af, bfr, acc[nt], 0, 0, 0);
    }
  }
  float* vkbh = vk + (size_t)bh * 65 * 64;
#pragma unroll
  for (int nt = 0; nt < 4; nt++)
#pragma unroll
    for (int r = 0; r < 4; r++)
      atomicAdd(&vkbh[(w * 16 + l4 * 4 + r) * 64 + nt * 16 + l16], acc[nt][r]);
#pragma unroll
  for (int j = 0; j < 8; j++)
#pragma unroll
    for (int off = 16; off > 0; off >>= 1)
      dsum[j] += __shfl_down(dsum[j], off, 32);
  if ((lane & 31) == 0)
#pragma unroll
    for (int j = 0; j < 8; j++)
      atomicAdd(&vkbh[64 * 64 + kd0 + j], dsum[j]);
}

// ---------------------------------------------------------------- res + div
__global__ __launch_bounds__(256) void res_attn(
    const bf16* __restrict__ qf, const float* __restrict__ vk,
    bf16* __restrict__ attn_x, bf16* __restrict__ attn_c) {
  __shared__ bf16 Bs[80][72];
  __shared__ float sden[256];
  int bh = blockIdx.x / 9, mblk = blockIdx.x % 9;
  int b = bh >> 4, h = bh & 15;
  int t = threadIdx.x, lane = t & 63, w = t >> 6;
  const float* vkp = vk + (size_t)bh * 65 * 64;
  for (int i = t; i < 80 * 64; i += 256) {
    int e = i >> 6, d = i & 63;
    Bs[e][d] = (bf16)(e < 65 ? vkp[i] : 0.f);
  }
  __syncthreads();
  int l16 = lane & 15, l4 = lane >> 4;
  const bf16* qbase = qf + (size_t)bh * S_SEQ * DHEAD;
  int q0w = mblk * 256 + w * 64;

  floatx4 acc[4][5] = {};
  bf16x8 af[4][2], bfr[5][2];
#pragma unroll
  for (int mt = 0; mt < 4; mt++) {
    int q = q0w + mt * 16 + l16;
    af[mt][0] = *(const bf16x8*)(qbase + (size_t)q * 64 + l4 * 8);
    af[mt][1] = *(const bf16x8*)(qbase + (size_t)q * 64 + 32 + l4 * 8);
  }
#pragma unroll
  for (int nt = 0; nt < 5; nt++) {
    bfr[nt][0] = *(const bf16x8*)&Bs[nt * 16 + l16][l4 * 8];
    bfr[nt][1] = *(const bf16x8*)&Bs[nt * 16 + l16][32 + l4 * 8];
  }
#pragma unroll
  for (int mt = 0; mt < 4; mt++)
#pragma unroll
    for (int nt = 0; nt < 5; nt++) {
      acc[mt][nt] = __builtin_amdgcn_mfma_f32_16x16x32_bf16(af[mt][0], bfr[nt][0], acc[mt][nt], 0, 0, 0);
      acc[mt][nt] = __builtin_amdgcn_mfma_f32_16x16x32_bf16(af[mt][1], bfr[nt][1], acc[mt][nt], 0, 0, 0);
    }
  // denominator: e=64 = col 0 of n-tile 4 (lanes with l16==0)
  if (l16 == 0) {
#pragma unroll
    for (int mt = 0; mt < 4; mt++)
#pragma unroll
      for (int r = 0; r < 4; r++)
        sden[w * 64 + mt * 16 + l4 * 4 + r] = acc[mt][4][r];
  }
  __syncthreads();
#pragma unroll
  for (int mt = 0; mt < 4; mt++)
#pragma unroll
    for (int r = 0; r < 4; r++) {
      float den = sden[w * 64 + mt * 16 + l4 * 4 + r] + LIN_EPS;
      float rden = 1.f / den;
      int q = q0w + mt * 16 + l4 * 4 + r;
#pragma unroll
      for (int nt = 0; nt < 4; nt++) {
        int dcol = nt * 16 + l16;
        float a = acc[mt][nt][r] * rden;
        if (q < L_SEQ)
          attn_x[((size_t)b * L_SEQ + q) * DMODEL + h * DHEAD + dcol] = (bf16)a;
        else
          attn_c[((size_t)b * C_SEQ + (q - L_SEQ)) * DMODEL + h * DHEAD + dcol] = (bf16)a;
      }
    }
}

// ---------------------------------------------------------------- final norm
__global__ __launch_bounds__(256) void final_norm(
    const bf16* __restrict__ y_x, const bf16* __restrict__ y_c,
    const float* __restrict__ g_out, const float* __restrict__ cg_out,
    float* __restrict__ out) {
  int g = blockIdx.x, t = threadIdx.x;
  const bf16* src;
  const float* gv;
  if (g < NBATCH * L_SEQ) {
    src = y_x + (size_t)g * DMODEL; gv = g_out;
  } else {
    int gg = g - NBATCH * L_SEQ;
    src = y_c + (size_t)gg * DMODEL; gv = cg_out;
  }
  float* dst = out + (size_t)g * DMODEL;
  int d0 = t * 4;
  bf16x4 y4 = *(const bf16x4*)(src + d0);
  float yv[4], p = 0.f;
#pragma unroll
  for (int i = 0; i < 4; i++) { yv[i] = (float)y4[i]; p += yv[i] * yv[i]; }
  int lane = t & 63, w = t >> 6;
  for (int off = 32; off > 0; off >>= 1) p += __shfl_down(p, off, 64);
  __shared__ float red[4];
  if (lane == 0) red[w] = p;
  __syncthreads();
  float ssum = red[0] + red[1] + red[2] + red[3];
  float sc = rsqrtf(ssum * (1.f / DMODEL) + RMS_EPS);
  floatx4 o;
#pragma unroll
  for (int i = 0; i < 4; i++) o[i] = yv[i] * sc * gv[d0 + i];
  *(floatx4*)(dst + d0) = o;
}

// ---------------------------------------------------------------- launch
extern "C" void kernel_launch(void* const* d_in, const int* in_sizes, int n_in,
                              void* d_out, int out_size, void* d_ws, size_t ws_size,
                              hipStream_t stream) {
  const float* x      = (const float*)d_in[0];
  const float* ctx    = (const float*)d_in[1];
  const int*   mask   = (const int*)d_in[2];
  const int*   spos   = (const int*)d_in[3];
  const float* Wqkv   = (const float*)d_in[4];
  const float* bqkv   = (const float*)d_in[5];
  const float* g_q    = (const float*)d_in[6];
  const float* g_k    = (const float*)d_in[7];
  const float* cWqkv  = (const float*)d_in[8];
  const float* cbqkv  = (const float*)d_in[9];
  const float* cg_q   = (const float*)d_in[10];
  const float* cg_k   = (const float*)d_in[11];
  const float* Wout   = (const float*)d_in[12];
  const float* bout   = (const float*)d_in[13];
  const float* g_out  = (const float*)d_in[14];
  const float* cWout  = (const float*)d_in[15];
  const float* cbout  = (const float*)d_in[16];
  const float* cg_out = (const float*)d_in[17];

  char* wsp = (char*)d_ws;
  size_t off = 0;
  auto alloc = [&](size_t bytes) -> void* {
    void* p = wsp + off;
    off += (bytes + 255) & ~(size_t)255;
    return p;
  };
  bf16* WqkvT  = (bf16*)alloc((size_t)3072 * 1024 * 2);
  bf16* cWqkvT = (bf16*)alloc((size_t)3072 * 1024 * 2);
  bf16* WoutT  = (bf16*)alloc((size_t)1024 * 1024 * 2);
  bf16* cWoutT = (bf16*)alloc((size_t)1024 * 1024 * 2);
  bf16* xbf    = (bf16*)alloc((size_t)NBATCH * L_SEQ * DMODEL * 2);
  bf16* cbf    = (bf16*)alloc((size_t)NBATCH * C_SEQ * DMODEL * 2);
  const size_t SLAB = (size_t)NBATCH * NHEAD * S_SEQ * DHEAD;  // 9,437,184
  bf16* qfs    = (bf16*)alloc(SLAB * 2);
  bf16* kfs    = (bf16*)alloc(SLAB * 2);
  bf16* vfs    = (bf16*)alloc(SLAB * 2);   // holds vT [bh][d][s]
  float* vkw   = (float*)alloc((size_t)64 * 65 * 64 * 4);
  float* rope  = (float*)alloc((size_t)NBATCH * L_SEQ * 64 * 4);
  int* anym    = (int*)alloc(256);
  // attn aliases kf slab (dead after vk_mfma); y aliases v slab.
  bf16* attn_x = kfs;
  bf16* attn_c = kfs + (size_t)NBATCH * L_SEQ * DMODEL;
  bf16* y_x    = vfs;
  bf16* y_c    = vfs + (size_t)NBATCH * L_SEQ * DMODEL;

  // 1) fused prep: transposes, converts, vkw zero, rope table, anymask
  prep<<<15112, 256, 0, stream>>>(Wqkv, cWqkv, Wout, cWout, x, ctx, mask, spos,
                                  WqkvT, cWqkvT, WoutT, cWoutT, xbf, cbf,
                                  vkw, rope, anym);

  // 2) QKV projections (x + ctx in one launch), 256^2 tile, 2 blocks/CU
  gemm_bias<true, true><<<dim3(12, 36), 512, 0, stream>>>(
      xbf, cbf, WqkvT, cWqkvT, bqkv, cbqkv, nullptr, nullptr,
      qfs, kfs, vfs, 3072, 1024, 32, 11, 0, 8, L_SEQ);

  // 3) in-place rmsnorm + rope + relu + mask on q/k slabs
  qkv_post<<<NBATCH * (L_SEQ + C_SEQ), 256, 0, stream>>>(
      qfs, kfs, mask, rope, anym, g_q, g_k, cg_q, cg_k);

  // 4) vk = vT kf via MFMA
  vk_mfma<<<64 * VK_CH, 256, 0, stream>>>(vfs, kfs, vkw);

  // 5) res = qf vk^T, divide, scatter to token-major (B,S,D)
  res_attn<<<576, 256, 0, stream>>>(qfs, vkw, attn_x, attn_c);

  // 6) output projections (x + ctx in one launch), 128^2 tile for grid size
  gemm_bias<false, false><<<dim3(8, 72), 256, 0, stream>>>(
      attn_x, attn_c, WoutT, cWoutT, bout, cbout, y_x, y_c,
      nullptr, nullptr, nullptr, 1024, 1024, 64, 0, 0, 0, 0);

  // 7) final rmsnorm -> FLOAT32 d_out (x_out rows then c_out rows)
  final_norm<<<NBATCH * (L_SEQ + C_SEQ), 256, 0, stream>>>(
      y_x, y_c, g_out, cg_out, (float*)d_out);
}

// Round 6
// 360.156 us; speedup vs baseline: 2.0431x; 2.0431x over previous
//
#include <hip/hip_runtime.h>

typedef __bf16 bf16;
typedef __bf16 bf16x4 __attribute__((ext_vector_type(4)));
typedef __bf16 bf16x8 __attribute__((ext_vector_type(8)));
typedef float  floatx4 __attribute__((ext_vector_type(4)));

#define L_SEQ   2048
#define C_SEQ   256
#define S_SEQ   2304
#define NBATCH  4
#define NHEAD   16
#define DHEAD   64
#define DMODEL  1024
#define RMS_EPS 1.1920928955078125e-07f
#define LIN_EPS 1e-6f

// async global->LDS, 16B per lane; LDS dest must be wave-uniform (+lane*16)
__device__ __forceinline__ void gload_lds16(const void* g, void* l) {
  __builtin_amdgcn_global_load_lds(
      (const __attribute__((address_space(1))) void*)g,
      (__attribute__((address_space(3))) void*)l, 16, 0, 0);
}

// ---------------------------------------------------------------- prep jobs
__device__ __forceinline__ void transpose_job(
    const float* __restrict__ src, bf16* __restrict__ dst,
    int R, int C, int tb, bf16 (*tile)[33]) {
  int tilesx = C >> 5;
  int c0 = (tb % tilesx) * 32, r0 = (tb / tilesx) * 32;
  int tx = threadIdx.x & 31, ty = threadIdx.x >> 5;
  for (int i = ty; i < 32; i += 8)
    tile[i][tx] = (bf16)src[(size_t)(r0 + i) * C + c0 + tx];
  __syncthreads();
  for (int i = ty; i < 32; i += 8)
    dst[(size_t)(c0 + i) * R + r0 + tx] = tile[tx][i];
}

__device__ __forceinline__ void convert_job(
    const float* __restrict__ src, bf16* __restrict__ dst, int tb) {
  size_t i = ((size_t)tb * 256 + threadIdx.x) * 8;
  floatx4 a = *(const floatx4*)(src + i);
  floatx4 b = *(const floatx4*)(src + i + 4);
  bf16x8 o;
#pragma unroll
  for (int j = 0; j < 4; j++) { o[j] = (bf16)a[j]; o[4 + j] = (bf16)b[j]; }
  *(bf16x8*)(dst + i) = o;
}

// One fused kernel for all independent prep work (block ranges in comments)
__global__ __launch_bounds__(256) void prep(
    const float* __restrict__ Wqkv, const float* __restrict__ cWqkv,
    const float* __restrict__ Wout, const float* __restrict__ cWout,
    const float* __restrict__ x, const float* __restrict__ ctx,
    const int* __restrict__ mask, const int* __restrict__ spos,
    bf16* __restrict__ WqkvT, bf16* __restrict__ cWqkvT,
    bf16* __restrict__ WoutT, bf16* __restrict__ cWoutT,
    bf16* __restrict__ xbf, bf16* __restrict__ cbf,
    float* __restrict__ vkw, float* __restrict__ rope,
    int* __restrict__ anym) {
  __shared__ bf16 tile[32][33];
  __shared__ int sh;
  int b = blockIdx.x;
  if (b < 3072) { transpose_job(Wqkv, WqkvT, 1024, 3072, b, tile); return; }
  b -= 3072;
  if (b < 3072) { transpose_job(cWqkv, cWqkvT, 1024, 3072, b, tile); return; }
  b -= 3072;
  if (b < 1024) { transpose_job(Wout, WoutT, 1024, 1024, b, tile); return; }
  b -= 1024;
  if (b < 1024) { transpose_job(cWout, cWoutT, 1024, 1024, b, tile); return; }
  b -= 1024;
  if (b < 4096) { convert_job(x, xbf, b); return; }
  b -= 4096;
  if (b < 512) { convert_job(ctx, cbf, b); return; }
  b -= 512;
  if (b < 260) {
    int i = b * 1024 + threadIdx.x * 4;
    *(floatx4*)(vkw + i) = floatx4{0.f, 0.f, 0.f, 0.f};
    return;
  }
  b -= 260;
  if (b < 2048) {
    // rope table: token = b*4 + t/64 (x tokens only), j = t&63, fi = j>>1
    int t = threadIdx.x;
    int tok = b * 4 + (t >> 6);
    int bb = tok >> 11, s = tok & 2047;
    int j = t & 63, fi = j >> 1;
    float ang = (float)(spos[bb] + s) * expf((float)fi * -0.28782313662425572f);
    rope[(size_t)tok * 64 + j] = (j & 1) ? sinf(ang) : cosf(ang);
    return;
  }
  b -= 2048;
  // anymask: any(mask[b][0][:])
  int a = 0;
  size_t base = (size_t)b * L_SEQ * L_SEQ;
  for (int j = threadIdx.x; j < L_SEQ; j += 256) a |= mask[base + j];
  if (threadIdx.x == 0) sh = 0;
  __syncthreads();
  if (a) atomicOr(&sh, 1);
  __syncthreads();
  if (threadIdx.x == 0) anym[b] = sh;
}

// ---------------------------------------------------------------- GEMM
// PROVEN R2 config: 128x128 tile, BK=32, 4 waves (2Mx2N), 2-phase dbuf
// (32 KiB LDS), ~3 blocks/CU (VGPR-bound) so inter-block TLP hides the
// per-K-step barrier drain. NO forced launch_bounds min-waves (R4 lesson:
// capping regs below acc size spills the accumulator to scratch).
// Bank swizzle (rotation, 64B rows of 4x16B slots): physical slot of
// logical slot c at row r is (c + (r>>1)) & 3 -> the 16 rows x 4 slots of
// a quarter-wave ds_read spread over all 8 bank-quads at exactly 2-way
// (free). Applied as pre-rotated GLOBAL source (gload_lds dest stays
// linear) + rotated ds_read offset; (r>>1)&3 reduces to lane bits because
// all row bases are multiples of 16.
// Pair launch: by < ybound -> part 1, else part 2. SCATTER: col ->
// (which={q,k,v}, h, dh); q/k head-major [bh][s][dh], v transposed
// [bh][dh][s] (bf16x4 store along s).
template <bool SCATTER>
__global__ __launch_bounds__(256) void gemm_bias(
    const bf16* __restrict__ A1, const bf16* __restrict__ A2,
    const bf16* __restrict__ B1t, const bf16* __restrict__ B2t,
    const float* __restrict__ bias1, const float* __restrict__ bias2,
    bf16* __restrict__ C1, bf16* __restrict__ C2,
    bf16* __restrict__ qs, bf16* __restrict__ ks, bf16* __restrict__ vs,
    int N, int K, int ybound,
    int rpb1, int soff1, int rpb2, int soff2) {
  __shared__ bf16 As[2][4096];   // [buf][128 rows x 32 elems], 64B rows
  __shared__ bf16 Bs[2][4096];

  // XCD-aware swizzle (all grids have nwg % 8 == 0)
  int nwg = gridDim.x * gridDim.y;
  int wg = blockIdx.y * gridDim.x + blockIdx.x;
  int cpx = nwg >> 3;
  wg = (wg & 7) * cpx + (wg >> 3);
  int bx = wg % gridDim.x, by = wg / gridDim.x;
  int n0 = bx * 128;
  const bf16 *Ap, *Bt;
  const float* bias;
  bf16* Cp;
  int m0, rpb, soff;
  if (by < ybound) {
    Ap = A1; Bt = B1t; bias = bias1; Cp = C1;
    m0 = by * 128; rpb = rpb1; soff = soff1;
  } else {
    Ap = A2; Bt = B2t; bias = bias2; Cp = C2;
    m0 = (by - ybound) * 128; rpb = rpb2; soff = soff2;
  }

  int t = threadIdx.x, lane = t & 63, w = t >> 6;
  int wm = (w & 1) * 64, wn = (w >> 1) * 64;
  int l16 = lane & 15, l4 = lane >> 4;

  // staging: chunk c = w*2+j covers rows [c*16, c*16+16); lane l -> row
  // c*16 + (l>>2), physical slot l&3. Content must be logical slot
  // (phys - (row>>1)) & 3 = ((l&3) - ((l>>3)&3)) & 3  (row>>1 mod 4 ==
  // (l>>3)&3 since chunk bases are multiples of 16).
  int crow = w * 32 + (lane >> 2);
  int scol = ((((lane & 3) - ((lane >> 3) & 3)) & 3)) << 3;
  const bf16* Ab = Ap + (size_t)(m0 + crow) * K + scol;
  const bf16* Bb = Bt + (size_t)(n0 + crow) * K + scol;

  auto stage = [&](int buf, int kb) {
#pragma unroll
    for (int j = 0; j < 2; j++) {
      gload_lds16(Ab + (size_t)(j * 16) * K + kb, (char*)As[buf] + (w * 2 + j) * 1024);
      gload_lds16(Bb + (size_t)(j * 16) * K + kb, (char*)Bs[buf] + (w * 2 + j) * 1024);
    }
  };

  // ds_read: logical slot l4 at row (base + l16), base % 16 == 0 ->
  // physical slot (l4 + (l16>>1)) & 3.
  int co = ((l4 + ((l16 >> 1) & 3)) & 3) << 3;
  int rba = (wm + l16) * 32 + co;   // + mt*512
  int rbb = (wn + l16) * 32 + co;   // + nt*512

  floatx4 acc[4][4] = {};
  stage(0, 0);
  __syncthreads();
  int NTt = K >> 5;
  for (int tt = 0; tt < NTt; ++tt) {
    int p = tt & 1;
    if (tt + 1 < NTt) stage(p ^ 1, (tt + 1) << 5);  // issue-early prefetch
    bf16x8 bfr[4];
#pragma unroll
    for (int nt = 0; nt < 4; nt++) bfr[nt] = *(const bf16x8*)&Bs[p][rbb + nt * 512];
    __builtin_amdgcn_s_setprio(1);
#pragma unroll
    for (int mt = 0; mt < 4; mt++) {
      bf16x8 a = *(const bf16x8*)&As[p][rba + mt * 512];
#pragma unroll
      for (int nt = 0; nt < 4; nt++)
        acc[mt][nt] = __builtin_amdgcn_mfma_f32_16x16x32_bf16(a, bfr[nt], acc[mt][nt], 0, 0, 0);
    }
    __builtin_amdgcn_s_setprio(0);
    __syncthreads();   // drains stage vmcnt; sibling blocks overlap this
  }

  // epilogue: D[row=(l>>4)*4+r][col=l&15] per 16x16 tile
#pragma unroll
  for (int mt = 0; mt < 4; mt++)
#pragma unroll
    for (int nt = 0; nt < 4; nt++) {
      int col = n0 + wn + nt * 16 + l16;
      float bval = bias[col];
      if constexpr (SCATTER) {
        int which = col >> 10;
        int h = (col >> 6) & 15;
        int dh = col & 63;
        int rmask = (1 << rpb) - 1;
        if (which == 2) {
          int rw0 = m0 + wm + mt * 16 + l4 * 4;
          int b = rw0 >> rpb;
          int s = soff + (rw0 & rmask);
          bf16x4 o;
#pragma unroll
          for (int r = 0; r < 4; r++) o[r] = (bf16)(acc[mt][nt][r] + bval);
          *(bf16x4*)(vs + ((size_t)(b * NHEAD + h) * DHEAD + dh) * S_SEQ + s) = o;
        } else {
          bf16* dst = which == 0 ? qs : ks;
#pragma unroll
          for (int r = 0; r < 4; r++) {
            int rw = m0 + wm + mt * 16 + l4 * 4 + r;
            int b = rw >> rpb;
            int s = soff + (rw & rmask);
            dst[((size_t)(b * NHEAD + h) * S_SEQ + s) * DHEAD + dh] =
                (bf16)(acc[mt][nt][r] + bval);
          }
        }
      } else {
#pragma unroll
        for (int r = 0; r < 4; r++) {
          int rw = m0 + wm + mt * 16 + l4 * 4 + r;
          Cp[(size_t)rw * N + col] = (bf16)(acc[mt][nt][r] + bval);
        }
      }
    }
}

// ---------------------------------------------------------------- qkv post
__global__ __launch_bounds__(256) void qkv_post(
    bf16* __restrict__ qs, bf16* __restrict__ ks,
    const int* __restrict__ mask, const float* __restrict__ rope,
    const int* __restrict__ anym,
    const float* __restrict__ g_q, const float* __restrict__ g_k,
    const float* __restrict__ cg_q, const float* __restrict__ cg_k) {
  int g = blockIdx.x, t = threadIdx.x;
  bool is_ctx = g >= NBATCH * L_SEQ;
  int b, s;
  const float *gq, *gk;
  float mval;
  if (!is_ctx) {
    b = g >> 11;
    int l = g & 2047;
    s = l;
    mval = mask[(size_t)b * L_SEQ * L_SEQ + l] ? 1.f : 0.f;  // mask[b][0][l]
    gq = g_q; gk = g_k;
  } else {
    int gg = g - NBATCH * L_SEQ;
    b = gg >> 8;
    s = L_SEQ + (gg & 255);
    mval = anym[b] ? 1.f : 0.f;
    gq = cg_q; gk = cg_k;
  }
  int d0 = t * 4;
  int h = t >> 4, dh = (t & 15) * 4;            // h*64+dh == d0
  size_t base = ((size_t)(b * NHEAD + h) * S_SEQ + s) * DHEAD + dh;
  bf16x4 q4 = *(const bf16x4*)(qs + base);
  bf16x4 k4 = *(const bf16x4*)(ks + base);
  float qv[4], kv[4], pq = 0.f, pk = 0.f;
#pragma unroll
  for (int i = 0; i < 4; i++) {
    qv[i] = (float)q4[i]; kv[i] = (float)k4[i];
    pq += qv[i] * qv[i];  pk += kv[i] * kv[i];
  }
  int lane = t & 63, w = t >> 6;
  for (int off = 32; off > 0; off >>= 1) {
    pq += __shfl_down(pq, off, 64);
    pk += __shfl_down(pk, off, 64);
  }
  __shared__ float red[8];
  if (lane == 0) { red[w] = pq; red[4 + w] = pk; }
  __syncthreads();
  float sq = red[0] + red[1] + red[2] + red[3];
  float sk = red[4] + red[5] + red[6] + red[7];
  float scq = rsqrtf(sq * (1.f / DMODEL) + RMS_EPS);
  float sck = rsqrtf(sk * (1.f / DMODEL) + RMS_EPS);
#pragma unroll
  for (int i = 0; i < 4; i++) {
    qv[i] *= scq * gq[d0 + i];
    kv[i] *= sck * gk[d0 + i];
  }
  if (!is_ctx) {
    floatx4 tb4 = *(const floatx4*)&rope[((size_t)(b << 11 | s)) * 64 + dh];
#pragma unroll
    for (int pr = 0; pr < 2; pr++) {
      float cc = tb4[2 * pr], ss = tb4[2 * pr + 1];
      float t0 = qv[2 * pr], t1 = qv[2 * pr + 1];
      qv[2 * pr]     = t0 * cc - t1 * ss;
      qv[2 * pr + 1] = t0 * ss + t1 * cc;
      t0 = kv[2 * pr]; t1 = kv[2 * pr + 1];
      kv[2 * pr]     = t0 * cc - t1 * ss;
      kv[2 * pr + 1] = t0 * ss + t1 * cc;
    }
  }
  bf16x4 qo, ko;
#pragma unroll
  for (int i = 0; i < 4; i++) {
    qo[i] = (bf16)fmaxf(qv[i], 0.f);
    ko[i] = (bf16)(fmaxf(kv[i], 0.f) * mval);
  }
  *(bf16x4*)(qs + base) = qo;
  *(bf16x4*)(ks + base) = ko;
}

// ---------------------------------------------------------------- vk (MFMA)
// vk[bh][e][d] = sum_s vT[bh][e][s] * kf[bh][s][d]; row e=64: sum_s kf[s][d].
// 1-barrier reg-staged double-buffer. Partials atomicAdd into zeroed vkw.
#define VK_CH   12
#define VK_SPAN (S_SEQ / VK_CH)   // 192 = 6 K-steps of 32
__global__ __launch_bounds__(256) void vk_mfma(
    const bf16* __restrict__ vT, const bf16* __restrict__ kf,
    float* __restrict__ vk) {
  __shared__ bf16 Vs[2][64][40];
  __shared__ bf16 Ks[2][64][40];   // Ks[d][s]
  int bh = blockIdx.x / VK_CH, chunk = blockIdx.x % VK_CH;
  int t = threadIdx.x, lane = t & 63, w = t >> 6;
  int l16 = lane & 15, l4 = lane >> 4;
  const bf16* vp = vT + (size_t)bh * DHEAD * S_SEQ;
  const bf16* kp = kf + (size_t)bh * S_SEQ * DHEAD;
  int s_begin = chunk * VK_SPAN;
  int ve = t >> 2, vso = (t & 3) * 8;        // v staging: row e, col offset
  int ks_s = t & 31, kd0 = (t >> 5) * 8;     // kf staging: s-slice, d-octet
  floatx4 acc[4] = {};
  float dsum[8] = {};
  bf16x8 vv = *(const bf16x8*)(vp + (size_t)ve * S_SEQ + s_begin + vso);
  bf16x8 kv = *(const bf16x8*)(kp + (size_t)(s_begin + ks_s) * DHEAD + kd0);
  for (int st = 0; st < VK_SPAN; st += 32) {
    int cur = (st >> 5) & 1;
    *(bf16x8*)&Vs[cur][ve][vso] = vv;
#pragma unroll
    for (int j = 0; j < 8; j++) {
      Ks[cur][kd0 + j][ks_s] = kv[j];
      dsum[j] += (float)kv[j];
    }
    if (st + 32 < VK_SPAN) {
      int s0 = s_begin + st + 32;
      vv = *(const bf16x8*)(vp + (size_t)ve * S_SEQ + s0 + vso);
      kv = *(const bf16x8*)(kp + (size_t)(s0 + ks_s) * DHEAD + kd0);
    }
    __syncthreads();
    bf16x8 af = *(const bf16x8*)&Vs[cur][w * 16 + l16][l4 * 8];
#pragma unroll
    for (int nt = 0; nt < 4; nt++) {
      bf16x8 bfr = *(const bf16x8*)&Ks[cur][nt * 16 + l16][l4 * 8];
      acc[nt] = __builtin_amdgcn_mfma_f32_16x16x32_bf16(af, bfr, acc[nt], 0, 0, 0);
    }
  }
  float* vkbh = vk + (size_t)bh * 65 * 64;
#pragma unroll
  for (int nt = 0; nt < 4; nt++)
#pragma unroll
    for (int r = 0; r < 4; r++)
      atomicAdd(&vkbh[(w * 16 + l4 * 4 + r) * 64 + nt * 16 + l16], acc[nt][r]);
#pragma unroll
  for (int j = 0; j < 8; j++)
#pragma unroll
    for (int off = 16; off > 0; off >>= 1)
      dsum[j] += __shfl_down(dsum[j], off, 32);
  if ((lane & 31) == 0)
#pragma unroll
    for (int j = 0; j < 8; j++)
      atomicAdd(&vkbh[64 * 64 + kd0 + j], dsum[j]);
}

// ---------------------------------------------------------------- res + div
__global__ __launch_bounds__(256) void res_attn(
    const bf16* __restrict__ qf, const float* __restrict__ vk,
    bf16* __restrict__ attn_x, bf16* __restrict__ attn_c) {
  __shared__ bf16 Bs[80][72];
  __shared__ float sden[256];
  int bh = blockIdx.x / 9, mblk = blockIdx.x % 9;
  int b = bh >> 4, h = bh & 15;
  int t = threadIdx.x, lane = t & 63, w = t >> 6;
  const float* vkp = vk + (size_t)bh * 65 * 64;
  for (int i = t; i < 80 * 64; i += 256) {
    int e = i >> 6, d = i & 63;
    Bs[e][d] = (bf16)(e < 65 ? vkp[i] : 0.f);
  }
  __syncthreads();
  int l16 = lane & 15, l4 = lane >> 4;
  const bf16* qbase = qf + (size_t)bh * S_SEQ * DHEAD;
  int q0w = mblk * 256 + w * 64;

  floatx4 acc[4][5] = {};
  bf16x8 af[4][2], bfr[5][2];
#pragma unroll
  for (int mt = 0; mt < 4; mt++) {
    int q = q0w + mt * 16 + l16;
    af[mt][0] = *(const bf16x8*)(qbase + (size_t)q * 64 + l4 * 8);
    af[mt][1] = *(const bf16x8*)(qbase + (size_t)q * 64 + 32 + l4 * 8);
  }
#pragma unroll
  for (int nt = 0; nt < 5; nt++) {
    bfr[nt][0] = *(const bf16x8*)&Bs[nt * 16 + l16][l4 * 8];
    bfr[nt][1] = *(const bf16x8*)&Bs[nt * 16 + l16][32 + l4 * 8];
  }
#pragma unroll
  for (int mt = 0; mt < 4; mt++)
#pragma unroll
    for (int nt = 0; nt < 5; nt++) {
      acc[mt][nt] = __builtin_amdgcn_mfma_f32_16x16x32_bf16(af[mt][0], bfr[nt][0], acc[mt][nt], 0, 0, 0);
      acc[mt][nt] = __builtin_amdgcn_mfma_f32_16x16x32_bf16(af[mt][1], bfr[nt][1], acc[mt][nt], 0, 0, 0);
    }
  // denominator: e=64 = col 0 of n-tile 4 (lanes with l16==0)
  if (l16 == 0) {
#pragma unroll
    for (int mt = 0; mt < 4; mt++)
#pragma unroll
      for (int r = 0; r < 4; r++)
        sden[w * 64 + mt * 16 + l4 * 4 + r] = acc[mt][4][r];
  }
  __syncthreads();
#pragma unroll
  for (int mt = 0; mt < 4; mt++)
#pragma unroll
    for (int r = 0; r < 4; r++) {
      float den = sden[w * 64 + mt * 16 + l4 * 4 + r] + LIN_EPS;
      float rden = 1.f / den;
      int q = q0w + mt * 16 + l4 * 4 + r;
#pragma unroll
      for (int nt = 0; nt < 4; nt++) {
        int dcol = nt * 16 + l16;
        float a = acc[mt][nt][r] * rden;
        if (q < L_SEQ)
          attn_x[((size_t)b * L_SEQ + q) * DMODEL + h * DHEAD + dcol] = (bf16)a;
        else
          attn_c[((size_t)b * C_SEQ + (q - L_SEQ)) * DMODEL + h * DHEAD + dcol] = (bf16)a;
      }
    }
}

// ---------------------------------------------------------------- final norm
__global__ __launch_bounds__(256) void final_norm(
    const bf16* __restrict__ y_x, const bf16* __restrict__ y_c,
    const float* __restrict__ g_out, const float* __restrict__ cg_out,
    float* __restrict__ out) {
  int g = blockIdx.x, t = threadIdx.x;
  const bf16* src;
  const float* gv;
  if (g < NBATCH * L_SEQ) {
    src = y_x + (size_t)g * DMODEL; gv = g_out;
  } else {
    int gg = g - NBATCH * L_SEQ;
    src = y_c + (size_t)gg * DMODEL; gv = cg_out;
  }
  float* dst = out + (size_t)g * DMODEL;
  int d0 = t * 4;
  bf16x4 y4 = *(const bf16x4*)(src + d0);
  float yv[4], p = 0.f;
#pragma unroll
  for (int i = 0; i < 4; i++) { yv[i] = (float)y4[i]; p += yv[i] * yv[i]; }
  int lane = t & 63, w = t >> 6;
  for (int off = 32; off > 0; off >>= 1) p += __shfl_down(p, off, 64);
  __shared__ float red[4];
  if (lane == 0) red[w] = p;
  __syncthreads();
  float ssum = red[0] + red[1] + red[2] + red[3];
  float sc = rsqrtf(ssum * (1.f / DMODEL) + RMS_EPS);
  floatx4 o;
#pragma unroll
  for (int i = 0; i < 4; i++) o[i] = yv[i] * sc * gv[d0 + i];
  *(floatx4*)(dst + d0) = o;
}

// ---------------------------------------------------------------- launch
extern "C" void kernel_launch(void* const* d_in, const int* in_sizes, int n_in,
                              void* d_out, int out_size, void* d_ws, size_t ws_size,
                              hipStream_t stream) {
  const float* x      = (const float*)d_in[0];
  const float* ctx    = (const float*)d_in[1];
  const int*   mask   = (const int*)d_in[2];
  const int*   spos   = (const int*)d_in[3];
  const float* Wqkv   = (const float*)d_in[4];
  const float* bqkv   = (const float*)d_in[5];
  const float* g_q    = (const float*)d_in[6];
  const float* g_k    = (const float*)d_in[7];
  const float* cWqkv  = (const float*)d_in[8];
  const float* cbqkv  = (const float*)d_in[9];
  const float* cg_q   = (const float*)d_in[10];
  const float* cg_k   = (const float*)d_in[11];
  const float* Wout   = (const float*)d_in[12];
  const float* bout   = (const float*)d_in[13];
  const float* g_out  = (const float*)d_in[14];
  const float* cWout  = (const float*)d_in[15];
  const float* cbout  = (const float*)d_in[16];
  const float* cg_out = (const float*)d_in[17];

  char* wsp = (char*)d_ws;
  size_t off = 0;
  auto alloc = [&](size_t bytes) -> void* {
    void* p = wsp + off;
    off += (bytes + 255) & ~(size_t)255;
    return p;
  };
  bf16* WqkvT  = (bf16*)alloc((size_t)3072 * 1024 * 2);
  bf16* cWqkvT = (bf16*)alloc((size_t)3072 * 1024 * 2);
  bf16* WoutT  = (bf16*)alloc((size_t)1024 * 1024 * 2);
  bf16* cWoutT = (bf16*)alloc((size_t)1024 * 1024 * 2);
  bf16* xbf    = (bf16*)alloc((size_t)NBATCH * L_SEQ * DMODEL * 2);
  bf16* cbf    = (bf16*)alloc((size_t)NBATCH * C_SEQ * DMODEL * 2);
  const size_t SLAB = (size_t)NBATCH * NHEAD * S_SEQ * DHEAD;  // 9,437,184
  bf16* qfs    = (bf16*)alloc(SLAB * 2);
  bf16* kfs    = (bf16*)alloc(SLAB * 2);
  bf16* vfs    = (bf16*)alloc(SLAB * 2);   // holds vT [bh][d][s]
  float* vkw   = (float*)alloc((size_t)64 * 65 * 64 * 4);
  float* rope  = (float*)alloc((size_t)NBATCH * L_SEQ * 64 * 4);
  int* anym    = (int*)alloc(256);
  // attn aliases kf slab (dead after vk_mfma); y aliases v slab.
  bf16* attn_x = kfs;
  bf16* attn_c = kfs + (size_t)NBATCH * L_SEQ * DMODEL;
  bf16* y_x    = vfs;
  bf16* y_c    = vfs + (size_t)NBATCH * L_SEQ * DMODEL;

  // 1) fused prep: transposes, converts, vkw zero, rope table, anymask
  prep<<<15112, 256, 0, stream>>>(Wqkv, cWqkv, Wout, cWout, x, ctx, mask, spos,
                                  WqkvT, cWqkvT, WoutT, cWoutT, xbf, cbf,
                                  vkw, rope, anym);

  // 2) QKV projections (x + ctx in one launch) -> head-major q/k + vT slabs
  gemm_bias<true><<<dim3(24, 72), 256, 0, stream>>>(
      xbf, cbf, WqkvT, cWqkvT, bqkv, cbqkv, nullptr, nullptr,
      qfs, kfs, vfs, 3072, 1024, 64, 11, 0, 8, L_SEQ);

  // 3) in-place rmsnorm + rope + relu + mask on q/k slabs
  qkv_post<<<NBATCH * (L_SEQ + C_SEQ), 256, 0, stream>>>(
      qfs, kfs, mask, rope, anym, g_q, g_k, cg_q, cg_k);

  // 4) vk = vT kf via MFMA
  vk_mfma<<<64 * VK_CH, 256, 0, stream>>>(vfs, kfs, vkw);

  // 5) res = qf vk^T, divide, scatter to token-major (B,S,D)
  res_attn<<<576, 256, 0, stream>>>(qfs, vkw, attn_x, attn_c);

  // 6) output projections (x + ctx in one launch)
  gemm_bias<false><<<dim3(8, 72), 256, 0, stream>>>(
      attn_x, attn_c, WoutT, cWoutT, bout, cbout, y_x, y_c,
      nullptr, nullptr, nullptr, 1024, 1024, 64, 0, 0, 0, 0);

  // 7) final rmsnorm -> FLOAT32 d_out (x_out rows then c_out rows)
  final_norm<<<NBATCH * (L_SEQ + C_SEQ), 256, 0, stream>>>(
      y_x, y_c, g_out, cg_out, (float*)d_out);
}